// Round 1
// baseline (81.725 us; speedup 1.0000x reference)
//
#include <hip/hip_runtime.h>
#include <hip/hip_bf16.h>

#define NCAM    16
#define IN      256
#define OUT     128
#define BATCH   8192
#define LISTCAP 1024              // per-cam list capacity (actual n_c ~= 512 +/- 22)
#define CHUNK   64                // samples per GEMM block
#define NCHUNK  (LISTCAP / CHUNK) // 16 chunk-blocks per cam (early-exit past n_c)

#define CONV_W_ITEMS (NCAM * OUT * IN / 8)   // 65536  (8 floats per item)
#define CONV_X_ITEMS (BATCH * IN / 8)        // 262144
#define NBLKA (NCAM + (CONV_W_ITEMS + CONV_X_ITEMS) / 256)  // 16 + 1280

typedef short bfx8 __attribute__((ext_vector_type(8)));   // MFMA A/B frag
typedef float fx4  __attribute__((ext_vector_type(4)));   // MFMA C/D frag

__device__ inline short f2bf(float f) {
    __hip_bfloat16 h = __float2bfloat16(f);   // RNE
    return *reinterpret_cast<short*>(&h);
}

__device__ inline float sigmoidf(float v) {
    return 1.0f / (1.0f + __expf(-v));
}

typedef const __attribute__((address_space(1))) unsigned int* gptr_t;
typedef __attribute__((address_space(3))) unsigned int* lptr_t;

// Direct global->LDS, 16 B/lane. LDS dest = wave-uniform base + lane*16 (linear).
__device__ inline void glds16(const void* g, void* l) {
    __builtin_amdgcn_global_load_lds((gptr_t)g, (lptr_t)l, 16, 0, 0);
}

// ---------------------------------------------------------------------------
// Kernel A: per-cam compaction (blocks 0..15) + fp32->bf16 convert of W and x
// into workspace (blocks 16..). Everything regenerated per iteration (ws is
// poisoned by the harness each iteration).
// ---------------------------------------------------------------------------
__global__ __launch_bounds__(256) void prep_kernel(
    const float* __restrict__ x,    // [BATCH, IN]
    const int*   __restrict__ cam,  // [BATCH]
    const float* __restrict__ W,    // [NCAM, OUT, IN]
    short*       __restrict__ xb,   // [BATCH, IN] bf16
    short*       __restrict__ wb,   // [NCAM, OUT, IN] bf16
    int*         __restrict__ cnt,  // [NCAM]
    int*         __restrict__ lists)// [NCAM, LISTCAP]
{
    const int tid = threadIdx.x;
    const int b   = blockIdx.x;

    if (b < NCAM) {
        // ---- compaction for camera c: count -> block prefix scan -> place ----
        __shared__ int pc[256];
        const int c = b;
        int cl = 0;
        for (int j = tid; j < BATCH; j += 256) cl += (cam[j] == c);
        pc[tid] = cl;
        __syncthreads();
        for (int s = 1; s < 256; s <<= 1) {       // Hillis-Steele inclusive scan
            int v = (tid >= s) ? pc[tid - s] : 0;
            __syncthreads();
            pc[tid] += v;
            __syncthreads();
        }
        if (tid == 255) cnt[c] = pc[255];
        int pos = pc[tid] - cl;                   // exclusive prefix
        for (int j = tid; j < BATCH; j += 256) {
            if (cam[j] == c) {
                if (pos < LISTCAP) lists[c * LISTCAP + pos] = j;
                ++pos;
            }
        }
    } else {
        // ---- convert: 8 floats -> 8 bf16 per thread, coalesced ----
        int idx = (b - NCAM) * 256 + tid;
        const float* src;
        short* dst;
        if (idx < CONV_W_ITEMS) {
            src = W  + (size_t)idx * 8;
            dst = wb + (size_t)idx * 8;
        } else {
            idx -= CONV_W_ITEMS;
            src = x  + (size_t)idx * 8;
            dst = xb + (size_t)idx * 8;
        }
        fx4 v0 = *(const fx4*)(src);
        fx4 v1 = *(const fx4*)(src + 4);
        bfx8 o;
        o[0] = f2bf(v0[0]); o[1] = f2bf(v0[1]); o[2] = f2bf(v0[2]); o[3] = f2bf(v0[3]);
        o[4] = f2bf(v1[0]); o[5] = f2bf(v1[1]); o[6] = f2bf(v1[2]); o[7] = f2bf(v1[3]);
        *(bfx8*)dst = o;
    }
}

// ---------------------------------------------------------------------------
// Kernel B: grouped GEMM. Block = (chunk of 64 samples, cam, out-half of 64).
// W and x staged via global_load_lds (16 B/lane) with XOR chunk-swizzle
// applied on the per-lane GLOBAL source (linear LDS dest), so stride-512B
// ds_read_b128 fragment reads are 2-way (free) instead of 16-way conflicted.
// One barrier; 32 MFMAs/wave; fused bias+sigmoid.
// ---------------------------------------------------------------------------
__global__ __launch_bounds__(256, 2) void gemm_kernel(
    const short* __restrict__ xb,
    const short* __restrict__ wb,
    const float* __restrict__ bias,
    const int*   __restrict__ cnt,
    const int*   __restrict__ lists,
    float*       __restrict__ out)
{
    __shared__ short __align__(16) s_x[CHUNK * IN];   // 32 KB, linear rows of 512 B
    __shared__ short __align__(16) s_w[CHUNK * IN];   // 32 KB
    __shared__ int s_list[CHUNK];

    const int chunk = blockIdx.x;
    const int c     = blockIdx.y;
    const int obase = blockIdx.z * 64;
    const int tid   = threadIdx.x;
    const int lane  = tid & 63;
    const int w     = tid >> 6;      // wave 0..3; owns outputs [obase+w*16, +16)
    const int oq    = lane & 15;
    const int quad  = lane >> 4;

    const int nc   = cnt[c];
    const int base = chunk * CHUNK;
    if (base >= nc) return;          // uniform exit
    const int m = min(CHUNK, nc - base);

    const int half = lane >> 5;      // which of 2 rows this lane stages
    const int cidx = lane & 31;      // 16B chunk within a 512B row

    // ---- stage W rows [obase, obase+64): independent of the list, issue first
    const short* wsrc = wb + (size_t)(c * OUT + obase) * IN;
    #pragma unroll
    for (int i = 0; i < 8; ++i) {
        int r  = w * 16 + i * 2 + half;
        int cs = cidx ^ (r & 7);                       // inverse swizzle on source
        glds16(wsrc + (size_t)r * IN + cs * 8, s_w + (w * 16 + i * 2) * IN);
    }

    // ---- list entries: LDS copy for epilogue; per-lane reads for x staging ----
    const int* lst = lists + c * LISTCAP + base;
    if (tid < CHUNK) s_list[tid] = lst[min(tid, m - 1)];

    #pragma unroll
    for (int i = 0; i < 8; ++i) {
        int r  = w * 16 + i * 2 + half;
        int g  = lst[min(r, m - 1)];                   // clamp: duplicate last row
        int cs = cidx ^ (r & 7);
        glds16(xb + (size_t)g * IN + cs * 8, s_x + (w * 16 + i * 2) * IN);
    }

    const float bo = bias[c * OUT + obase + w * 16 + oq];
    __syncthreads();   // drains vmcnt (glds) + covers s_list

    // ---- MFMA: 4 sample-tiles x 16 outputs, K=256 ----
    bfx8 bf[8];
    #pragma unroll
    for (int kk = 0; kk < 8; ++kk) {
        int cs = (kk * 4 + quad) ^ (oq & 7);           // swizzled read
        bf[kk] = *(const bfx8*)(s_w + (w * 16 + oq) * IN + cs * 8);
    }
    fx4 zero = {0.f, 0.f, 0.f, 0.f};
    fx4 acc[4] = {zero, zero, zero, zero};
    #pragma unroll
    for (int st = 0; st < 4; ++st) {
        #pragma unroll
        for (int kk = 0; kk < 8; ++kk) {
            int cs = (kk * 4 + quad) ^ (oq & 7);
            bfx8 a = *(const bfx8*)(s_x + (st * 16 + oq) * IN + cs * 8);
            acc[st] = __builtin_amdgcn_mfma_f32_16x16x32_bf16(a, bf[kk], acc[st], 0, 0, 0);
        }
    }

    // ---- epilogue: bias + sigmoid + scatter (C/D: col=oq, row=quad*4+r) ----
    #pragma unroll
    for (int st = 0; st < 4; ++st) {
        #pragma unroll
        for (int r = 0; r < 4; ++r) {
            int s = st * 16 + quad * 4 + r;
            if (s < m) {
                int g = s_list[s];
                out[(size_t)g * OUT + obase + w * 16 + oq] = sigmoidf(acc[st][r] + bo);
            }
        }
    }
}

extern "C" void kernel_launch(void* const* d_in, const int* in_sizes, int n_in,
                              void* d_out, int out_size, void* d_ws, size_t ws_size,
                              hipStream_t stream) {
    const float* x    = (const float*)d_in[0];
    const int*   cam  = (const int*)d_in[1];
    const float* W    = (const float*)d_in[2];
    const float* bias = (const float*)d_in[3];
    float* out = (float*)d_out;

    char* ws = (char*)d_ws;
    short* xb  = (short*)ws;                                   // 4 MB bf16 x
    short* wb  = (short*)(ws + (size_t)BATCH * IN * 2);        // 1 MB bf16 W
    int*   cnt = (int*)(ws + (size_t)BATCH * IN * 2 + (size_t)NCAM * OUT * IN * 2);
    int*   lists = cnt + 64;                                   // 256 B after cnt

    prep_kernel<<<dim3(NBLKA), 256, 0, stream>>>(x, cam, W, xb, wb, cnt, lists);
    gemm_kernel<<<dim3(NCHUNK, NCAM, 2), 256, 0, stream>>>(xb, wb, bias, cnt, lists, out);
}

// Round 2
// 74.753 us; speedup vs baseline: 1.0933x; 1.0933x over previous
//
#include <hip/hip_runtime.h>
#include <hip/hip_bf16.h>

#define NCAM   16
#define IN     256
#define OUT    128
#define BATCH  8192
#define NSLICE 8
#define SLICE  (BATCH / NSLICE)    // 1024 samples per block's scan range
#define OHALF  64                  // outputs per block (z-split by 2)
#define XROW   (IN + 8)            // padded bf16 row stride (528 B): 2-way banks = free
#define CHUNK  64                  // gathered samples per MFMA round

typedef short bfx8 __attribute__((ext_vector_type(8)));   // MFMA A/B frag (4 VGPRs)
typedef short bfx4 __attribute__((ext_vector_type(4)));
typedef float fx4  __attribute__((ext_vector_type(4)));   // MFMA C/D frag

__device__ inline short f2bf(float f) {
    __hip_bfloat16 h = __float2bfloat16(f);   // RNE
    return *reinterpret_cast<short*>(&h);
}

__device__ inline float sigmoidf(float v) {
    return 1.0f / (1.0f + __expf(-v));
}

// Block = (slice of 1024, camera, out-half of 64): 256 blocks = 1/CU, 8 waves.
// One-pass 8-wave ballot compaction; W staged coalesced -> bf16 LDS (4x less
// W traffic than the 32-slice version); W fragments hoisted to registers once;
// x gathered in 64-row chunks; 16x16x32 MFMA; fused bias+sigmoid.
__global__ __launch_bounds__(512, 2) void fc_expert_kernel(
    const float* __restrict__ x,     // [BATCH, IN] fp32
    const int*   __restrict__ cam,   // [BATCH]
    const float* __restrict__ W,     // [NCAM, OUT, IN] fp32
    const float* __restrict__ bias,  // [NCAM, OUT] fp32
    float*       __restrict__ out)   // [BATCH, OUT] fp32
{
    __shared__ int   s_list[SLICE];
    __shared__ int   s_cnt[16];
    __shared__ short __align__(16) s_w[OHALF * XROW];  // 33.8 KB bf16 W strip
    __shared__ short __align__(16) s_x[CHUNK * XROW];  // 33.8 KB x chunk

    const int slice = blockIdx.x;
    const int c     = blockIdx.y;
    const int obase = blockIdx.z * OHALF;
    const int tid   = threadIdx.x;
    const int lane  = tid & 63;
    const int w     = tid >> 6;          // wave 0..7
    const int w4    = w & 3;             // out-group: outputs [obase+w4*16, +16)
    const int base  = slice * SLICE;
    const int oq    = lane & 15;
    const int quad  = lane >> 4;

    // ---- issue scan loads first (needed earliest) ----
    const int g0 = base + w * 128 + lane;
    const int g1 = g0 + 64;
    const int c0 = cam[g0];
    const int c1 = cam[g1];

    // ---- issue W row loads: wave w stages rows {w, w+8, ..., w+56} ----
    const float* wp = W + (size_t)(c * OUT + obase) * IN;
    fx4 wv[8];
    #pragma unroll
    for (int i = 0; i < 8; ++i)
        wv[i] = *(const fx4*)(wp + (size_t)(w + 8 * i) * IN + lane * 4);

    const float bo = bias[c * OUT + obase + w4 * 16 + oq];

    // ---- one-pass compaction: each wave ballots two 64-sample groups ----
    const bool f0 = (c0 == c), f1 = (c1 == c);
    const unsigned long long b0 = __ballot(f0);
    const unsigned long long b1 = __ballot(f1);
    if (lane == 0) { s_cnt[w * 2] = __popcll(b0); s_cnt[w * 2 + 1] = __popcll(b1); }

    // ---- convert staged W rows to bf16 in LDS (8 B/lane: 2-way banks, free) ----
    #pragma unroll
    for (int i = 0; i < 8; ++i) {
        fx4 v = wv[i];
        bfx4 sv;
        sv[0] = f2bf(v[0]); sv[1] = f2bf(v[1]); sv[2] = f2bf(v[2]); sv[3] = f2bf(v[3]);
        *(bfx4*)(s_w + (w + 8 * i) * XROW + lane * 4) = sv;
    }
    __syncthreads();   // s_cnt + s_w visible

    // ---- prefix over the 16 ballot groups; scatter indices ----
    int off0 = 0, mtot = 0;
    #pragma unroll
    for (int k = 0; k < 16; ++k) {
        int v = s_cnt[k];
        off0 += (k < w * 2) ? v : 0;
        mtot += v;
    }
    const int m = mtot;
    const unsigned long long pm = (1ull << lane) - 1ull;
    if (f0) s_list[off0 + __popcll(b0 & pm)] = g0;
    if (f1) s_list[off0 + __popcll(b0) + __popcll(b1 & pm)] = g1;

    // ---- hoist this wave's 8 W fragments to registers (reused every chunk) ----
    bfx8 bfrag[8];
    #pragma unroll
    for (int kk = 0; kk < 8; ++kk)
        bfrag[kk] = *(const bfx8*)(s_w + (w4 * 16 + oq) * XROW + kk * 32 + quad * 8);

    __syncthreads();   // s_list visible

    for (int cb = 0; cb < m; cb += CHUNK) {
        // ---- stage up to 64 gathered x rows (wave w: rows {w, w+8, ...}) ----
        #pragma unroll
        for (int j = 0; j < 8; ++j) {
            int row = w + 8 * j;
            int li  = cb + row;
            bfx4 sv = {0, 0, 0, 0};
            if (li < m) {               // wave-uniform branch
                int g = s_list[li];
                fx4 v = *(const fx4*)(x + (size_t)g * IN + lane * 4);
                sv[0] = f2bf(v[0]); sv[1] = f2bf(v[1]); sv[2] = f2bf(v[2]); sv[3] = f2bf(v[3]);
            }
            *(bfx4*)(s_x + row * XROW + lane * 4) = sv;
        }
        __syncthreads();

        // ---- MFMA: wave handles sample-tiles {(w>>2)*2, +1}, 16 outs, K=256 ----
        #pragma unroll
        for (int u = 0; u < 2; ++u) {
            int t = (w >> 2) * 2 + u;
            fx4 acc = {0.f, 0.f, 0.f, 0.f};
            #pragma unroll
            for (int kk = 0; kk < 8; ++kk) {
                bfx8 a = *(const bfx8*)(s_x + (t * 16 + oq) * XROW + kk * 32 + quad * 8);
                acc = __builtin_amdgcn_mfma_f32_16x16x32_bf16(a, bfrag[kk], acc, 0, 0, 0);
            }
            // epilogue: bias + sigmoid + scatter (C/D: col=oq, row=quad*4+r)
            #pragma unroll
            for (int r = 0; r < 4; ++r) {
                int s = cb + t * 16 + quad * 4 + r;
                if (s < m) {
                    int g = s_list[s];
                    out[(size_t)g * OUT + obase + w4 * 16 + oq] = sigmoidf(acc[r] + bo);
                }
            }
        }
        __syncthreads();   // s_x reads done before next chunk's staging
    }
}

extern "C" void kernel_launch(void* const* d_in, const int* in_sizes, int n_in,
                              void* d_out, int out_size, void* d_ws, size_t ws_size,
                              hipStream_t stream) {
    const float* x    = (const float*)d_in[0];
    const int*   cam  = (const int*)d_in[1];
    const float* W    = (const float*)d_in[2];
    const float* bias = (const float*)d_in[3];
    float* out = (float*)d_out;

    dim3 grid(NSLICE, NCAM, 2);
    fc_expert_kernel<<<grid, 512, 0, stream>>>(x, cam, W, bias, out);
}